// Round 4
// baseline (228.670 us; speedup 1.0000x reference)
//
#include <hip/hip_runtime.h>
#include <hip/hip_bf16.h>

#define B_ 2
#define S_ 2048
#define D_ 1024
#define H_ 16
#define DEPTH_ 64

typedef __attribute__((ext_vector_type(4))) float f32x4;
typedef __attribute__((ext_vector_type(8))) short bf16x8;
typedef const __attribute__((address_space(1))) unsigned int gu32;
typedef __attribute__((address_space(3))) unsigned int lu32;

__device__ __forceinline__ void gload_lds16(const void* g, void* l) {
  __builtin_amdgcn_global_load_lds((gu32*)g, (lu32*)l, 16, 0, 0);
}

__device__ __forceinline__ short f2bf(float f) {
  union { float f; unsigned u; } v; v.f = f;
  return (short)((v.u + 0x7FFFu + ((v.u >> 16) & 1u)) >> 16);
}

// ---------- cast fp32 -> bf16 (4 elems/thread) ----------
__global__ __launch_bounds__(256) void cast_kernel(const float* __restrict__ in,
                                                   short* __restrict__ out, int n4) {
  int i = blockIdx.x * 256 + threadIdx.x;
  if (i < n4) {
    const float4 v = reinterpret_cast<const float4*>(in)[i];
    short4 o;
    o.x = f2bf(v.x); o.y = f2bf(v.y); o.z = f2bf(v.z); o.w = f2bf(v.w);
    reinterpret_cast<short4*>(out)[i] = o;
  }
}

// ---------- transpose + cast: W[K][N] f32 -> WT[N][K] bf16 ----------
__global__ __launch_bounds__(256) void transpose_cast_kernel(const float* __restrict__ W,
                                                             short* __restrict__ WT,
                                                             int K, int N) {
  __shared__ short tile[32][33];
  int n0 = blockIdx.x * 32, k0 = blockIdx.y * 32;
  int tx = threadIdx.x, ty = threadIdx.y;
#pragma unroll
  for (int j = 0; j < 4; ++j)
    tile[ty + 8 * j][tx] = f2bf(W[(size_t)(k0 + ty + 8 * j) * N + n0 + tx]);
  __syncthreads();
#pragma unroll
  for (int j = 0; j < 4; ++j)
    WT[(size_t)(n0 + ty + 8 * j) * K + k0 + tx] = tile[tx][ty + 8 * j];
}

// ---------- GEMM (m97 structure): C = A[M][K] * BT[N][K]^T + bias ----------
template <int EPI>
__global__ __launch_bounds__(256) void gemm_bt_kernel(
    const short* __restrict__ A, const short* __restrict__ BT,
    const float* __restrict__ bias,
    short* __restrict__ Qh, short* __restrict__ Kh, short* __restrict__ VTt,
    float* __restrict__ Out, int M, int N, int K) {
  __shared__ short As[128 * 64];
  __shared__ short Bs[128 * 64];
  const int bm = blockIdx.y * 128, bn = blockIdx.x * 128;
  const int tid = threadIdx.x;
  const int wave = tid >> 6, lane = tid & 63;
  const int wr = wave >> 1, wc = wave & 1;      // 2x2 wave grid, 64x64 each
  const int lr = lane & 15, lg = lane >> 4;
  const int srow = wave * 32 + (lane >> 3);     // staging row (+i*8)
  const int scol = (lane & 7) * 8;              // staging col (shorts)
  f32x4 acc[4][4] = {};
  const int nk = K >> 6;
  for (int kt = 0; kt < nk; ++kt) {
    __syncthreads();
    const short* pa = &A[(size_t)(bm + srow) * K + kt * 64 + scol];
    const short* pb = &BT[(size_t)(bn + srow) * K + kt * 64 + scol];
#pragma unroll
    for (int i = 0; i < 4; ++i) {
      gload_lds16(pa + (size_t)(i * 8) * K, &As[(wave * 32 + i * 8) * 64]);
      gload_lds16(pb + (size_t)(i * 8) * K, &Bs[(wave * 32 + i * 8) * 64]);
    }
    __syncthreads();
#pragma unroll
    for (int ks = 0; ks < 2; ++ks) {
      bf16x8 af[4], bfr[4];
#pragma unroll
      for (int mi = 0; mi < 4; ++mi)
        af[mi] = *reinterpret_cast<const bf16x8*>(&As[(64 * wr + 16 * mi + lr) * 64 + 8 * lg + 32 * ks]);
#pragma unroll
      for (int ni = 0; ni < 4; ++ni)
        bfr[ni] = *reinterpret_cast<const bf16x8*>(&Bs[(64 * wc + 16 * ni + lr) * 64 + 8 * lg + 32 * ks]);
#pragma unroll
      for (int mi = 0; mi < 4; ++mi)
#pragma unroll
        for (int ni = 0; ni < 4; ++ni)
          acc[mi][ni] = __builtin_amdgcn_mfma_f32_16x16x32_bf16(af[mi], bfr[ni], acc[mi][ni], 0, 0, 0);
    }
  }
  // epilogue: D layout col = lane&15, row = 4*(lane>>4)+r  [m89 verified]
#pragma unroll
  for (int mi = 0; mi < 4; ++mi) {
#pragma unroll
    for (int ni = 0; ni < 4; ++ni) {
#pragma unroll
      for (int r = 0; r < 4; ++r) {
        int row = bm + 64 * wr + 16 * mi + 4 * lg + r;
        int col = bn + 64 * wc + 16 * ni + lr;
        float v = acc[mi][ni][r] + bias[col];
        if (EPI == 0) {
          int b = row >> 11, s = row & (S_ - 1);
          int which = col >> 10, cm = col & (D_ - 1);
          int h = cm >> 6, dd = cm & 63;
          short bv = f2bf(v);
          size_t bh = (size_t)(b * H_ + h);
          if (which == 0)      Qh[(bh * S_ + s) * DEPTH_ + dd] = bv;
          else if (which == 1) Kh[(bh * S_ + s) * DEPTH_ + dd] = bv;
          else                 VTt[(bh * DEPTH_ + dd) * S_ + s] = bv;
        } else {
          Out[(size_t)row * N + col] = v;
        }
      }
    }
  }
}

// ---------- flash attention: 512 blocks = 32 bh x 16 pairs of q-tiles ----------
// No K/V LDS staging: fragments straight from global (L1/L2-resident after
// the QKV GEMM). Zero barriers in the kv loop -> free software pipelining.
__global__ __launch_bounds__(256) void attn_kernel(
    const short* __restrict__ Qh, const short* __restrict__ Kh,
    const short* __restrict__ VTt, const float* __restrict__ mask,
    short* __restrict__ ctx) {
  constexpr int LK = 72;  // 64 + 8 pad
  constexpr float LOG2E = 1.44269504f;
  __shared__ short Ps[4][16 * LK];    // per-wave P strip [q][kv]
  const int bid = blockIdx.x;
  const int pr = bid & 15, bh = bid >> 4;
  const int b = bh >> 4, h = bh & 15;
  const short* Qp = Qh + (size_t)bh * S_ * DEPTH_;
  const short* Kp = Kh + (size_t)bh * S_ * DEPTH_;
  const short* Vp = VTt + (size_t)bh * DEPTH_ * S_;
  const int tid = threadIdx.x;
  const int wave = tid >> 6, lane = tid & 63;
  const int lr = lane & 15, lg = lane >> 4;

  for (int half = 0; half < 2; ++half) {
    const int qt = half == 0 ? (31 - pr) : pr;
    const int q0 = qt * 64;
    const int nt = qt + 1;

    // Q fragments in registers (wave owns q rows [q0+16*wave, +16))
    bf16x8 qf[2];
    {
      int qrow = q0 + 16 * wave + lr;
      qf[0] = *reinterpret_cast<const bf16x8*>(&Qp[(size_t)qrow * DEPTH_ + 8 * lg]);
      qf[1] = *reinterpret_cast<const bf16x8*>(&Qp[(size_t)qrow * DEPTH_ + 32 + 8 * lg]);
    }
    float m_run[4], l_run[4];
    f32x4 acc_o[4] = {};
#pragma unroll
    for (int r = 0; r < 4; ++r) { m_run[r] = -1e30f; l_run[r] = 0.f; }

    for (int kt = 0; kt < nt; ++kt) {
      const int k0 = kt * 64;

      // S = Q K^T : K fragments direct from global (cached)
      f32x4 sc[4];
#pragma unroll
      for (int f = 0; f < 4; ++f) { f32x4 z = {0.f, 0.f, 0.f, 0.f}; sc[f] = z; }
#pragma unroll
      for (int ks = 0; ks < 2; ++ks) {
#pragma unroll
        for (int f = 0; f < 4; ++f) {
          bf16x8 kf = *reinterpret_cast<const bf16x8*>(
              &Kp[(size_t)(k0 + 16 * f + lr) * DEPTH_ + 8 * lg + 32 * ks]);
          sc[f] = __builtin_amdgcn_mfma_f32_16x16x32_bf16(qf[ks], kf, sc[f], 0, 0, 0);
        }
      }
      // scale (log2 domain) + additive mask + causal (diagonal tile only)
      constexpr float SC = 0.125f * LOG2E;
#pragma unroll
      for (int f = 0; f < 4; ++f) {
        float mv = mask[(size_t)b * S_ + k0 + 16 * f + lr] * LOG2E;
#pragma unroll
        for (int r = 0; r < 4; ++r) {
          float s = sc[f][r] * SC + mv;
          if (kt == nt - 1) {
            int qq = 16 * wave + 4 * lg + r;
            int kk = 16 * f + lr;
            if (kk > qq) s -= 2e9f;
          }
          sc[f][r] = s;
        }
      }
      // online softmax
#pragma unroll
      for (int r = 0; r < 4; ++r) {
        float m = fmaxf(fmaxf(sc[0][r], sc[1][r]), fmaxf(sc[2][r], sc[3][r]));
#pragma unroll
        for (int off = 1; off < 16; off <<= 1) m = fmaxf(m, __shfl_xor(m, off));
        float m_new = fmaxf(m_run[r], m);
        float corr = exp2f(m_run[r] - m_new);
        float su = 0.f;
#pragma unroll
        for (int f = 0; f < 4; ++f) {
          float p = exp2f(sc[f][r] - m_new);
          sc[f][r] = p;
          su += p;
        }
#pragma unroll
        for (int off = 1; off < 16; off <<= 1) su += __shfl_xor(su, off);
        l_run[r] = l_run[r] * corr + su;
        m_run[r] = m_new;
#pragma unroll
        for (int df = 0; df < 4; ++df) acc_o[df][r] *= corr;
      }
      // P -> wave-private LDS strip (same-wave write/read, no barrier)
#pragma unroll
      for (int f = 0; f < 4; ++f)
#pragma unroll
        for (int r = 0; r < 4; ++r)
          Ps[wave][(4 * lg + r) * LK + 16 * f + lr] = f2bf(sc[f][r]);
      // ctx += P V : V^T fragments direct from global (cached)
#pragma unroll
      for (int ks = 0; ks < 2; ++ks) {
        bf16x8 ap = *reinterpret_cast<const bf16x8*>(&Ps[wave][lr * LK + 8 * lg + 32 * ks]);
#pragma unroll
        for (int df = 0; df < 4; ++df) {
          bf16x8 bv = *reinterpret_cast<const bf16x8*>(
              &Vp[(size_t)(16 * df + lr) * S_ + k0 + 8 * lg + 32 * ks]);
          acc_o[df] = __builtin_amdgcn_mfma_f32_16x16x32_bf16(ap, bv, acc_o[df], 0, 0, 0);
        }
      }
    }
    // epilogue: ctx[b][q][h*64+d] bf16 (merged-head layout for out-proj)
#pragma unroll
    for (int df = 0; df < 4; ++df) {
#pragma unroll
      for (int r = 0; r < 4; ++r) {
        int q = q0 + 16 * wave + 4 * lg + r;
        int col = h * 64 + 16 * df + lr;
        float v = acc_o[df][r] / l_run[r];
        ctx[((size_t)b * S_ + q) * D_ + col] = f2bf(v);
      }
    }
  }
}

extern "C" void kernel_launch(void* const* d_in, const int* in_sizes, int n_in,
                              void* d_out, int out_size, void* d_ws, size_t ws_size,
                              hipStream_t stream) {
  const float* X    = (const float*)d_in[0];
  const float* mask = (const float*)d_in[1];
  const float* Wqkv = (const float*)d_in[2];
  const float* bqkv = (const float*)d_in[3];
  const float* Wout = (const float*)d_in[4];
  const float* bout = (const float*)d_in[5];
  float* Out = (float*)d_out;

  short* ws    = (short*)d_ws;
  short* Xb    = ws;                                   // 4096*1024 bf16
  short* WqkvT = Xb + (size_t)4096 * 1024;             // [3072][1024]
  short* WoutT = WqkvT + (size_t)3072 * 1024;          // [1024][1024]
  short* Qh    = WoutT + (size_t)1024 * 1024;          // [bh][s][64]
  short* Kh    = Qh + (size_t)B_ * H_ * S_ * DEPTH_;   // [bh][s][64]
  short* VTt   = Kh + (size_t)B_ * H_ * S_ * DEPTH_;   // [bh][64][s]
  short* ctx   = VTt + (size_t)B_ * H_ * S_ * DEPTH_;  // [b][s][1024]

  cast_kernel<<<4096, 256, 0, stream>>>(X, Xb, (4096 * 1024) / 4);
  transpose_cast_kernel<<<dim3(96, 32), dim3(32, 8), 0, stream>>>(Wqkv, WqkvT, 1024, 3072);
  transpose_cast_kernel<<<dim3(32, 32), dim3(32, 8), 0, stream>>>(Wout, WoutT, 1024, 1024);
  gemm_bt_kernel<0><<<dim3(24, 32), 256, 0, stream>>>(Xb, WqkvT, bqkv, Qh, Kh, VTt, nullptr,
                                                      4096, 3072, 1024);
  attn_kernel<<<512, 256, 0, stream>>>(Qh, Kh, VTt, mask, ctx);
  gemm_bt_kernel<1><<<dim3(8, 32), 256, 0, stream>>>(ctx, WoutT, bout, nullptr, nullptr, nullptr,
                                                     Out, 4096, 1024, 1024);
}

// Round 5
// 186.408 us; speedup vs baseline: 1.2267x; 1.2267x over previous
//
#include <hip/hip_runtime.h>
#include <hip/hip_bf16.h>

#define B_ 2
#define S_ 2048
#define D_ 1024
#define H_ 16
#define DEPTH_ 64

typedef __attribute__((ext_vector_type(4))) float f32x4;
typedef __attribute__((ext_vector_type(16))) float f32x16;
typedef __attribute__((ext_vector_type(8))) short bf16x8;
typedef const __attribute__((address_space(1))) unsigned int gu32;
typedef __attribute__((address_space(3))) unsigned int lu32;

__device__ __forceinline__ void gload_lds16(const void* g, void* l) {
  __builtin_amdgcn_global_load_lds((gu32*)g, (lu32*)l, 16, 0, 0);
}

__device__ __forceinline__ short f2bf(float f) {
  union { float f; unsigned u; } v; v.f = f;
  return (short)((v.u + 0x7FFFu + ((v.u >> 16) & 1u)) >> 16);
}
__device__ __forceinline__ unsigned pk2(float lo, float hi) {
  return ((unsigned)(unsigned short)f2bf(hi) << 16) | (unsigned short)f2bf(lo);
}

// ---------- cast fp32 -> bf16 (4 elems/thread) ----------
__global__ __launch_bounds__(256) void cast_kernel(const float* __restrict__ in,
                                                   short* __restrict__ out, int n4) {
  int i = blockIdx.x * 256 + threadIdx.x;
  if (i < n4) {
    const float4 v = reinterpret_cast<const float4*>(in)[i];
    short4 o;
    o.x = f2bf(v.x); o.y = f2bf(v.y); o.z = f2bf(v.z); o.w = f2bf(v.w);
    reinterpret_cast<short4*>(out)[i] = o;
  }
}

// ---------- transpose + cast: W[K][N] f32 -> WT[N][K] bf16 ----------
__global__ __launch_bounds__(256) void transpose_cast_kernel(const float* __restrict__ W,
                                                             short* __restrict__ WT,
                                                             int K, int N) {
  __shared__ short tile[32][33];
  int n0 = blockIdx.x * 32, k0 = blockIdx.y * 32;
  int tx = threadIdx.x, ty = threadIdx.y;
#pragma unroll
  for (int j = 0; j < 4; ++j)
    tile[ty + 8 * j][tx] = f2bf(W[(size_t)(k0 + ty + 8 * j) * N + n0 + tx]);
  __syncthreads();
#pragma unroll
  for (int j = 0; j < 4; ++j)
    WT[(size_t)(n0 + ty + 8 * j) * K + k0 + tx] = tile[tx][ty + 8 * j];
}

// ---------- GEMM (m97 structure): C = A[M][K] * BT[N][K]^T + bias ----------
template <int EPI>
__global__ __launch_bounds__(256) void gemm_bt_kernel(
    const short* __restrict__ A, const short* __restrict__ BT,
    const float* __restrict__ bias,
    short* __restrict__ Qh, short* __restrict__ Kh, short* __restrict__ VTt,
    float* __restrict__ Out, int M, int N, int K) {
  __shared__ short As[128 * 64];
  __shared__ short Bs[128 * 64];
  const int bm = blockIdx.y * 128, bn = blockIdx.x * 128;
  const int tid = threadIdx.x;
  const int wave = tid >> 6, lane = tid & 63;
  const int wr = wave >> 1, wc = wave & 1;
  const int lr = lane & 15, lg = lane >> 4;
  const int srow = wave * 32 + (lane >> 3);
  const int scol = (lane & 7) * 8;
  f32x4 acc[4][4] = {};
  const int nk = K >> 6;
  for (int kt = 0; kt < nk; ++kt) {
    __syncthreads();
    const short* pa = &A[(size_t)(bm + srow) * K + kt * 64 + scol];
    const short* pb = &BT[(size_t)(bn + srow) * K + kt * 64 + scol];
#pragma unroll
    for (int i = 0; i < 4; ++i) {
      gload_lds16(pa + (size_t)(i * 8) * K, &As[(wave * 32 + i * 8) * 64]);
      gload_lds16(pb + (size_t)(i * 8) * K, &Bs[(wave * 32 + i * 8) * 64]);
    }
    __syncthreads();
#pragma unroll
    for (int ks = 0; ks < 2; ++ks) {
      bf16x8 af[4], bfr[4];
#pragma unroll
      for (int mi = 0; mi < 4; ++mi)
        af[mi] = *reinterpret_cast<const bf16x8*>(&As[(64 * wr + 16 * mi + lr) * 64 + 8 * lg + 32 * ks]);
#pragma unroll
      for (int ni = 0; ni < 4; ++ni)
        bfr[ni] = *reinterpret_cast<const bf16x8*>(&Bs[(64 * wc + 16 * ni + lr) * 64 + 8 * lg + 32 * ks]);
#pragma unroll
      for (int mi = 0; mi < 4; ++mi)
#pragma unroll
        for (int ni = 0; ni < 4; ++ni)
          acc[mi][ni] = __builtin_amdgcn_mfma_f32_16x16x32_bf16(af[mi], bfr[ni], acc[mi][ni], 0, 0, 0);
    }
  }
#pragma unroll
  for (int mi = 0; mi < 4; ++mi) {
#pragma unroll
    for (int ni = 0; ni < 4; ++ni) {
#pragma unroll
      for (int r = 0; r < 4; ++r) {
        int row = bm + 64 * wr + 16 * mi + 4 * lg + r;
        int col = bn + 64 * wc + 16 * ni + lr;
        float v = acc[mi][ni][r] + bias[col];
        if (EPI == 0) {
          int b = row >> 11, s = row & (S_ - 1);
          int which = col >> 10, cm = col & (D_ - 1);
          int h = cm >> 6, dd = cm & 63;
          short bv = f2bf(v);
          size_t bh = (size_t)(b * H_ + h);
          if (which == 0)      Qh[(bh * S_ + s) * DEPTH_ + dd] = bv;
          else if (which == 1) Kh[(bh * S_ + s) * DEPTH_ + dd] = bv;
          else                 VTt[(bh * DEPTH_ + dd) * S_ + s] = bv;
        } else {
          Out[(size_t)row * N + col] = v;
        }
      }
    }
  }
}

// ---------- flash attention, 32x32 swapped-operand (m214 structure) ----------
// 1024 blocks = 32 qt (heavy-first) x 32 bh; 128 threads = 2 waves x 32 q-rows.
// S^T = mfma(K,Q): lane owns q-col = lane&31 -> in-register softmax (1 shuffle).
// ctx^T = mfma(V^T, P): corr/l stay lane-local. K/V staged via global_load_lds
// with XOR-swizzled source (T2/m173): conflict-free ds_read_b128.
__global__ __launch_bounds__(128) void attn_kernel(
    const short* __restrict__ Qh, const short* __restrict__ Kh,
    const short* __restrict__ VTt, const float* __restrict__ mask,
    short* __restrict__ ctx) {
  constexpr float SC = 0.125f * 1.44269504f;  // scale * log2(e)
  __shared__ short Ks[64 * 64];   // [kv][d] swizzled
  __shared__ short Vs[64 * 64];   // [d][kv] swizzled
  const int bid = blockIdx.x;
  const int qt = 31 - (bid >> 5);        // heavy-first for backfill balance
  const int bh = bid & 31;
  const int b = bh >> 4, h = bh & 15;
  const short* Qp = Qh + (size_t)bh * S_ * DEPTH_;
  const short* Kp = Kh + (size_t)bh * S_ * DEPTH_;
  const short* Vp = VTt + (size_t)bh * DEPTH_ * S_;
  const int tid = threadIdx.x;
  const int w = tid >> 6, lane = tid & 63;
  const int lq = lane & 31, hi = lane >> 5;
  const int q0w = qt * 64 + w * 32;      // this wave's 32 q-rows
  const int scs = 8 * ((lane & 7) ^ ((lane >> 3) & 7));  // swizzled src col (shorts)
  const int srw = lane >> 3;                              // src row offset 0..7

  // Q fragments: qf[ksd] = Q[q=lq][d = 16*ksd + 8*hi .. +7]
  bf16x8 qf[4];
#pragma unroll
  for (int ksd = 0; ksd < 4; ++ksd)
    qf[ksd] = *reinterpret_cast<const bf16x8*>(&Qp[(size_t)(q0w + lq) * DEPTH_ + 16 * ksd + 8 * hi]);

  // ones B-frag for the mask-MFMA (B[q][0] = 1 held by hi=0 lanes)
  bf16x8 ones = {};
  if (hi == 0) ones[0] = (short)0x3F80;

  f32x16 acc0 = {}, acc1 = {};   // ctx^T accum: D[d][q], dh = 0,1
  float m_run = -1e30f, l_run = 0.f;

  const int nt = qt + 1;
  for (int kt = 0; kt < nt; ++kt) {
    const int k0 = kt * 64;
    __syncthreads();
    // stage K[64][64] and V^T[64][64], source-swizzled so LDS[row][c] = M[row][c^(row&7)]
#pragma unroll
    for (int j = 0; j < 4; ++j) {
      const int brow = w * 32 + j * 8;
      gload_lds16(&Kp[(size_t)(k0 + brow + srw) * DEPTH_ + scs], &Ks[brow * 64]);
      gload_lds16(&Vp[(size_t)(brow + srw) * S_ + k0 + scs], &Vs[brow * 64]);
    }
    __syncthreads();

    // S^T[kv][q] accum per kv-half
    f32x16 sc[2] = {{}, {}};
#pragma unroll
    for (int h2 = 0; h2 < 2; ++h2) {
#pragma unroll
      for (int ksd = 0; ksd < 4; ++ksd) {
        const int row = h2 * 32 + lq;
        const int col = (16 * ksd + 8 * hi) ^ ((row & 7) * 8);
        bf16x8 kf = *reinterpret_cast<const bf16x8*>(&Ks[row * 64 + col]);
        sc[h2] = __builtin_amdgcn_mfma_f32_32x32x16_bf16(kf, qf[ksd], sc[h2], 0, 0, 0);
      }
      // add 8*mask[kv] via one MFMA (A[kv][0] = 8*mask, B[q][0] = 1)
      float mv = mask[(size_t)b * S_ + k0 + h2 * 32 + lq];
      bf16x8 maf = {};
      if (hi == 0) maf[0] = f2bf(8.f * mv);
      sc[h2] = __builtin_amdgcn_mfma_f32_32x32x16_bf16(maf, ones, sc[h2], 0, 0, 0);
    }
    // causal (last tile only): kv row per reg = (r&3)+8*(r>>2)+4*hi+32*h2
    if (kt == nt - 1) {
      const int qg = q0w + lq;
#pragma unroll
      for (int h2 = 0; h2 < 2; ++h2)
#pragma unroll
        for (int r = 0; r < 16; ++r) {
          int kvg = k0 + (r & 3) + 8 * (r >> 2) + 4 * hi + 32 * h2;
          if (kvg > qg) sc[h2][r] = -1e30f;
        }
    }
    // in-register softmax over the lane's 32 kv values + partner combine
    float mx = sc[0][0];
#pragma unroll
    for (int r = 1; r < 16; ++r) mx = fmaxf(mx, sc[0][r]);
#pragma unroll
    for (int r = 0; r < 16; ++r) mx = fmaxf(mx, sc[1][r]);
    mx = fmaxf(mx, __shfl_xor(mx, 32));
    const float m_tile = mx * SC;
    const float m_new = fmaxf(m_run, m_tile);
    const float corr = exp2f(m_run - m_new);
    m_run = m_new;
    float su = 0.f;
#pragma unroll
    for (int h2 = 0; h2 < 2; ++h2)
#pragma unroll
      for (int r = 0; r < 16; ++r) {
        float p = exp2f(fmaf(sc[h2][r], SC, -m_new));
        sc[h2][r] = p;
        su += p;
      }
    su += __shfl_xor(su, 32);
    l_run = l_run * corr + su;
#pragma unroll
    for (int r = 0; r < 16; ++r) { acc0[r] *= corr; acc1[r] *= corr; }

    // PV: pack P rows into B-frags in-register (4 pk + 2x2 shuffle-selects per ks)
#pragma unroll
    for (int h2 = 0; h2 < 2; ++h2) {
#pragma unroll
      for (int ks = 0; ks < 2; ++ks) {
        const int rb = 8 * ks;
        unsigned a = pk2(sc[h2][rb + 0], sc[h2][rb + 1]);
        unsigned bq = pk2(sc[h2][rb + 2], sc[h2][rb + 3]);
        unsigned c = pk2(sc[h2][rb + 4], sc[h2][rb + 5]);
        unsigned d = pk2(sc[h2][rb + 6], sc[h2][rb + 7]);
        unsigned sa = __shfl_xor((int)a, 32), sb = __shfl_xor((int)bq, 32);
        unsigned sx = __shfl_xor((int)c, 32), sy = __shfl_xor((int)d, 32);
        union { unsigned u[4]; bf16x8 v; } pf;
        pf.u[0] = hi ? sx : a;
        pf.u[1] = hi ? sy : bq;
        pf.u[2] = hi ? c : sa;
        pf.u[3] = hi ? d : sb;
#pragma unroll
        for (int dh = 0; dh < 2; ++dh) {
          const int row = dh * 32 + lq;
          const int col = (32 * h2 + 16 * ks + 8 * hi) ^ ((row & 7) * 8);
          bf16x8 vf = *reinterpret_cast<const bf16x8*>(&Vs[row * 64 + col]);
          if (dh == 0) acc0 = __builtin_amdgcn_mfma_f32_32x32x16_bf16(vf, pf.v, acc0, 0, 0, 0);
          else         acc1 = __builtin_amdgcn_mfma_f32_32x32x16_bf16(vf, pf.v, acc1, 0, 0, 0);
        }
      }
    }
  }

  // epilogue: normalize, transpose via LDS (reuse staging), coalesced store
  const float rl = 1.f / l_run;
  __syncthreads();
  short* ob = Ks;  // 64 rows x 72 stride (shorts), fits in Ks+Vs
#pragma unroll
  for (int dh = 0; dh < 2; ++dh) {
    const f32x16& A = dh ? acc1 : acc0;
#pragma unroll
    for (int g = 0; g < 4; ++g)
#pragma unroll
      for (int p = 0; p < 2; ++p) {
        int r0 = 4 * g + 2 * p;
        int d0 = 2 * p + 8 * g + 4 * hi + 32 * dh;
        unsigned u = pk2(A[r0] * rl, A[r0 + 1] * rl);
        *reinterpret_cast<unsigned*>(&ob[(w * 32 + lq) * 72 + d0]) = u;
      }
  }
  __syncthreads();
  {
    const int row = tid >> 1, half = tid & 1;
    short* dst = ctx + ((size_t)b * S_ + qt * 64 + row) * D_ + h * 64 + half * 32;
    const short* srcp = &ob[row * 72 + half * 32];
#pragma unroll
    for (int c = 0; c < 4; ++c)
      *reinterpret_cast<bf16x8*>(&dst[8 * c]) = *reinterpret_cast<const bf16x8*>(&srcp[8 * c]);
  }
}

extern "C" void kernel_launch(void* const* d_in, const int* in_sizes, int n_in,
                              void* d_out, int out_size, void* d_ws, size_t ws_size,
                              hipStream_t stream) {
  const float* X    = (const float*)d_in[0];
  const float* mask = (const float*)d_in[1];
  const float* Wqkv = (const float*)d_in[2];
  const float* bqkv = (const float*)d_in[3];
  const float* Wout = (const float*)d_in[4];
  const float* bout = (const float*)d_in[5];
  float* Out = (float*)d_out;

  short* ws    = (short*)d_ws;
  short* Xb    = ws;                                   // 4096*1024 bf16
  short* WqkvT = Xb + (size_t)4096 * 1024;             // [3072][1024]
  short* WoutT = WqkvT + (size_t)3072 * 1024;          // [1024][1024]
  short* Qh    = WoutT + (size_t)1024 * 1024;          // [bh][s][64]
  short* Kh    = Qh + (size_t)B_ * H_ * S_ * DEPTH_;   // [bh][s][64]
  short* VTt   = Kh + (size_t)B_ * H_ * S_ * DEPTH_;   // [bh][64][s]
  short* ctx   = VTt + (size_t)B_ * H_ * S_ * DEPTH_;  // [b][s][1024]

  cast_kernel<<<4096, 256, 0, stream>>>(X, Xb, (4096 * 1024) / 4);
  transpose_cast_kernel<<<dim3(96, 32), dim3(32, 8), 0, stream>>>(Wqkv, WqkvT, 1024, 3072);
  transpose_cast_kernel<<<dim3(32, 32), dim3(32, 8), 0, stream>>>(Wout, WoutT, 1024, 1024);
  gemm_bt_kernel<0><<<dim3(24, 32), 256, 0, stream>>>(Xb, WqkvT, bqkv, Qh, Kh, VTt, nullptr,
                                                      4096, 3072, 1024);
  attn_kernel<<<1024, 128, 0, stream>>>(Qh, Kh, VTt, mask, ctx);
  gemm_bt_kernel<1><<<dim3(8, 32), 256, 0, stream>>>(ctx, WoutT, bout, nullptr, nullptr, nullptr,
                                                     Out, 4096, 1024, 1024);
}

// Round 6
// 155.956 us; speedup vs baseline: 1.4662x; 1.1953x over previous
//
#include <hip/hip_runtime.h>
#include <hip/hip_bf16.h>

#define B_ 2
#define S_ 2048
#define D_ 1024
#define H_ 16
#define DEPTH_ 64

typedef __attribute__((ext_vector_type(4))) float f32x4;
typedef __attribute__((ext_vector_type(16))) float f32x16;
typedef __attribute__((ext_vector_type(8))) short bf16x8;
typedef const __attribute__((address_space(1))) unsigned int gu32;
typedef __attribute__((address_space(3))) unsigned int lu32;

__device__ __forceinline__ void gload_lds16(const void* g, void* l) {
  __builtin_amdgcn_global_load_lds((gu32*)g, (lu32*)l, 16, 0, 0);
}

__device__ __forceinline__ short f2bf(float f) {
  union { float f; unsigned u; } v; v.f = f;
  return (short)((v.u + 0x7FFFu + ((v.u >> 16) & 1u)) >> 16);
}
__device__ __forceinline__ unsigned pk2(float lo, float hi) {
  return ((unsigned)(unsigned short)f2bf(hi) << 16) | (unsigned short)f2bf(lo);
}

// ---------- cast fp32 -> bf16 (4 elems/thread) ----------
__global__ __launch_bounds__(256) void cast_kernel(const float* __restrict__ in,
                                                   short* __restrict__ out, int n4) {
  int i = blockIdx.x * 256 + threadIdx.x;
  if (i < n4) {
    const float4 v = reinterpret_cast<const float4*>(in)[i];
    short4 o;
    o.x = f2bf(v.x); o.y = f2bf(v.y); o.z = f2bf(v.z); o.w = f2bf(v.w);
    reinterpret_cast<short4*>(out)[i] = o;
  }
}

// ---------- transpose + cast: W[K][N] f32 -> WT[N][K] bf16 ----------
__global__ __launch_bounds__(256) void transpose_cast_kernel(const float* __restrict__ W,
                                                             short* __restrict__ WT,
                                                             int K, int N) {
  __shared__ short tile[32][33];
  int n0 = blockIdx.x * 32, k0 = blockIdx.y * 32;
  int tx = threadIdx.x, ty = threadIdx.y;
#pragma unroll
  for (int j = 0; j < 4; ++j)
    tile[ty + 8 * j][tx] = f2bf(W[(size_t)(k0 + ty + 8 * j) * N + n0 + tx]);
  __syncthreads();
#pragma unroll
  for (int j = 0; j < 4; ++j)
    WT[(size_t)(n0 + ty + 8 * j) * K + k0 + tx] = tile[tx][ty + 8 * j];
}

// ---------- GEMM (m97 structure): C = A[M][K] * BT[N][K]^T + bias ----------
template <int EPI>
__global__ __launch_bounds__(256) void gemm_bt_kernel(
    const short* __restrict__ A, const short* __restrict__ BT,
    const float* __restrict__ bias,
    short* __restrict__ Qh, short* __restrict__ Kh, short* __restrict__ VTt,
    float* __restrict__ Out, int M, int N, int K) {
  __shared__ short As[128 * 64];
  __shared__ short Bs[128 * 64];
  const int bm = blockIdx.y * 128, bn = blockIdx.x * 128;
  const int tid = threadIdx.x;
  const int wave = tid >> 6, lane = tid & 63;
  const int wr = wave >> 1, wc = wave & 1;
  const int lr = lane & 15, lg = lane >> 4;
  const int srow = wave * 32 + (lane >> 3);
  const int scol = (lane & 7) * 8;
  f32x4 acc[4][4] = {};
  const int nk = K >> 6;
  for (int kt = 0; kt < nk; ++kt) {
    __syncthreads();
    const short* pa = &A[(size_t)(bm + srow) * K + kt * 64 + scol];
    const short* pb = &BT[(size_t)(bn + srow) * K + kt * 64 + scol];
#pragma unroll
    for (int i = 0; i < 4; ++i) {
      gload_lds16(pa + (size_t)(i * 8) * K, &As[(wave * 32 + i * 8) * 64]);
      gload_lds16(pb + (size_t)(i * 8) * K, &Bs[(wave * 32 + i * 8) * 64]);
    }
    __syncthreads();
#pragma unroll
    for (int ks = 0; ks < 2; ++ks) {
      bf16x8 af[4], bfr[4];
#pragma unroll
      for (int mi = 0; mi < 4; ++mi)
        af[mi] = *reinterpret_cast<const bf16x8*>(&As[(64 * wr + 16 * mi + lr) * 64 + 8 * lg + 32 * ks]);
#pragma unroll
      for (int ni = 0; ni < 4; ++ni)
        bfr[ni] = *reinterpret_cast<const bf16x8*>(&Bs[(64 * wc + 16 * ni + lr) * 64 + 8 * lg + 32 * ks]);
#pragma unroll
      for (int mi = 0; mi < 4; ++mi)
#pragma unroll
        for (int ni = 0; ni < 4; ++ni)
          acc[mi][ni] = __builtin_amdgcn_mfma_f32_16x16x32_bf16(af[mi], bfr[ni], acc[mi][ni], 0, 0, 0);
    }
  }
#pragma unroll
  for (int mi = 0; mi < 4; ++mi) {
#pragma unroll
    for (int ni = 0; ni < 4; ++ni) {
#pragma unroll
      for (int r = 0; r < 4; ++r) {
        int row = bm + 64 * wr + 16 * mi + 4 * lg + r;
        int col = bn + 64 * wc + 16 * ni + lr;
        float v = acc[mi][ni][r] + bias[col];
        if (EPI == 0) {
          int b = row >> 11, s = row & (S_ - 1);
          int which = col >> 10, cm = col & (D_ - 1);
          int h = cm >> 6, dd = cm & 63;
          short bv = f2bf(v);
          size_t bh = (size_t)(b * H_ + h);
          if (which == 0)      Qh[(bh * S_ + s) * DEPTH_ + dd] = bv;
          else if (which == 1) Kh[(bh * S_ + s) * DEPTH_ + dd] = bv;
          else                 VTt[(bh * DEPTH_ + dd) * S_ + s] = bv;
        } else {
          Out[(size_t)row * N + col] = v;
        }
      }
    }
  }
}

// ---------- flash attention, 32x32 swapped-operand + split-KV ----------
// 1024 blocks = 32 qt x 32 bh; 256 threads = 4 waves.
// wave w: q-strip (w&1), kv-chunk (w>>1). Chunk0 = tiles [0,nh), chunk1 = [nh,nt).
// Each chunk's wave-pair stages its own K/V tile; in-block merge of (m,l,acc).
__global__ __launch_bounds__(256, 4) void attn_kernel(
    const short* __restrict__ Qh, const short* __restrict__ Kh,
    const short* __restrict__ VTt, const float* __restrict__ mask,
    short* __restrict__ ctx) {
  constexpr float SC = 0.125f * 1.44269504f;  // scale * log2(e)
  __shared__ short smem[16384];  // 32KB: [chunk][K 4096 | V 4096] shorts
  const int bid = blockIdx.x;
  const int qt = 31 - (bid >> 5);
  const int bh = bid & 31;
  const int b = bh >> 4, h = bh & 15;
  const short* Qp = Qh + (size_t)bh * S_ * DEPTH_;
  const short* Kp = Kh + (size_t)bh * S_ * DEPTH_;
  const short* Vp = VTt + (size_t)bh * DEPTH_ * S_;
  const int tid = threadIdx.x;
  const int w = tid >> 6, lane = tid & 63;
  const int sw = w & 1, ch = w >> 1;
  const int lq = lane & 31, hi = lane >> 5;
  const int q0w = qt * 64 + sw * 32;     // this wave's 32 q-rows
  const int scs = 8 * ((lane & 7) ^ ((lane >> 3) & 7));  // swizzled src col (shorts)
  const int srw = lane >> 3;                              // src row offset 0..7
  short* Ksc = smem + ch * 8192;
  short* Vsc = Ksc + 4096;

  // Q fragments: qf[ksd] = Q[q=lq][d = 16*ksd + 8*hi .. +7]
  bf16x8 qf[4];
#pragma unroll
  for (int ksd = 0; ksd < 4; ++ksd)
    qf[ksd] = *reinterpret_cast<const bf16x8*>(&Qp[(size_t)(q0w + lq) * DEPTH_ + 16 * ksd + 8 * hi]);

  // ones B-frag for the mask-MFMA (B[q][0] = 1 held by hi=0 lanes)
  bf16x8 ones = {};
  if (hi == 0) ones[0] = (short)0x3F80;

  f32x16 acc0 = {}, acc1 = {};   // ctx^T accum: D[d][q], dh = 0,1
  float m_run = -1e30f, l_run = 0.f;

  const int nt = qt + 1;
  const int nh = (nt + 1) >> 1;  // chunk0 tile count (>= chunk1)
  for (int i = 0; i < nh; ++i) {
    const int kt = ch ? (nh + i) : i;
    const bool valid = kt < nt;
    const int k0 = kt * 64;
    __syncthreads();
    if (valid) {
#pragma unroll
      for (int j = 0; j < 4; ++j) {
        const int brow = sw * 32 + j * 8;
        gload_lds16(&Kp[(size_t)(k0 + brow + srw) * DEPTH_ + scs], &Ksc[brow * 64]);
        gload_lds16(&Vp[(size_t)(brow + srw) * S_ + k0 + scs], &Vsc[brow * 64]);
      }
    }
    __syncthreads();
    if (!valid) continue;

    // S^T[kv][q] accum per kv-half
    f32x16 sc[2] = {{}, {}};
#pragma unroll
    for (int h2 = 0; h2 < 2; ++h2) {
#pragma unroll
      for (int ksd = 0; ksd < 4; ++ksd) {
        const int row = h2 * 32 + lq;
        const int col = (16 * ksd + 8 * hi) ^ ((row & 7) * 8);
        bf16x8 kf = *reinterpret_cast<const bf16x8*>(&Ksc[row * 64 + col]);
        sc[h2] = __builtin_amdgcn_mfma_f32_32x32x16_bf16(kf, qf[ksd], sc[h2], 0, 0, 0);
      }
      // add 8*mask[kv] via one MFMA (A[kv][0] = 8*mask, B[q][0] = 1)
      float mv = mask[(size_t)b * S_ + k0 + h2 * 32 + lq];
      bf16x8 maf = {};
      if (hi == 0) maf[0] = f2bf(8.f * mv);
      sc[h2] = __builtin_amdgcn_mfma_f32_32x32x16_bf16(maf, ones, sc[h2], 0, 0, 0);
    }
    // causal (diag tile only): kv row per reg = (r&3)+8*(r>>2)+4*hi+32*h2
    if (kt == nt - 1) {
      const int qg = q0w + lq;
#pragma unroll
      for (int h2 = 0; h2 < 2; ++h2)
#pragma unroll
        for (int r = 0; r < 16; ++r) {
          int kvg = k0 + (r & 3) + 8 * (r >> 2) + 4 * hi + 32 * h2;
          if (kvg > qg) sc[h2][r] = -1e30f;
        }
    }
    // in-register softmax over the lane's 32 kv values + partner combine
    float mx = sc[0][0];
#pragma unroll
    for (int r = 1; r < 16; ++r) mx = fmaxf(mx, sc[0][r]);
#pragma unroll
    for (int r = 0; r < 16; ++r) mx = fmaxf(mx, sc[1][r]);
    mx = fmaxf(mx, __shfl_xor(mx, 32));
    const float m_tile = mx * SC;
    const float m_new = fmaxf(m_run, m_tile);
    const float corr = exp2f(m_run - m_new);
    m_run = m_new;
    float su = 0.f;
#pragma unroll
    for (int h2 = 0; h2 < 2; ++h2)
#pragma unroll
      for (int r = 0; r < 16; ++r) {
        float p = exp2f(fmaf(sc[h2][r], SC, -m_new));
        sc[h2][r] = p;
        su += p;
      }
    su += __shfl_xor(su, 32);
    l_run = l_run * corr + su;
#pragma unroll
    for (int r = 0; r < 16; ++r) { acc0[r] *= corr; acc1[r] *= corr; }

    // PV: pack P rows into B-frags in-register
#pragma unroll
    for (int h2 = 0; h2 < 2; ++h2) {
#pragma unroll
      for (int ks = 0; ks < 2; ++ks) {
        const int rb = 8 * ks;
        unsigned a = pk2(sc[h2][rb + 0], sc[h2][rb + 1]);
        unsigned bq = pk2(sc[h2][rb + 2], sc[h2][rb + 3]);
        unsigned c = pk2(sc[h2][rb + 4], sc[h2][rb + 5]);
        unsigned d = pk2(sc[h2][rb + 6], sc[h2][rb + 7]);
        unsigned sa = __shfl_xor((int)a, 32), sb = __shfl_xor((int)bq, 32);
        unsigned sx = __shfl_xor((int)c, 32), sy = __shfl_xor((int)d, 32);
        union { unsigned u[4]; bf16x8 v; } pf;
        pf.u[0] = hi ? sx : a;
        pf.u[1] = hi ? sy : bq;
        pf.u[2] = hi ? c : sa;
        pf.u[3] = hi ? d : sb;
#pragma unroll
        for (int dh = 0; dh < 2; ++dh) {
          const int row = dh * 32 + lq;
          const int col = (32 * h2 + 16 * ks + 8 * hi) ^ ((row & 7) * 8);
          bf16x8 vf = *reinterpret_cast<const bf16x8*>(&Vsc[row * 64 + col]);
          if (dh == 0) acc0 = __builtin_amdgcn_mfma_f32_32x32x16_bf16(vf, pf.v, acc0, 0, 0, 0);
          else         acc1 = __builtin_amdgcn_mfma_f32_32x32x16_bf16(vf, pf.v, acc1, 0, 0, 0);
        }
      }
    }
  }

  // ---- in-block merge of kv-chunks, then normalize + transpose + store ----
  __syncthreads();
  float* F  = (float*)smem;              // [strip][lane][32] partials from chunk1
  float* ML = (float*)(smem + 8192);     // [strip][lane][2]  (m, l)
  short* ob = smem + 8704;               // [64 q][72] transposed output
  if (ch == 1) {
    float* dst = F + ((size_t)sw * 64 + lane) * 32;
#pragma unroll
    for (int r = 0; r < 16; ++r) { dst[r] = acc0[r]; dst[16 + r] = acc1[r]; }
    ML[(sw * 64 + lane) * 2 + 0] = m_run;
    ML[(sw * 64 + lane) * 2 + 1] = l_run;
  }
  __syncthreads();
  if (ch == 0) {
    const float* src = F + ((size_t)sw * 64 + lane) * 32;
    const float m1 = ML[(sw * 64 + lane) * 2 + 0];
    const float l1 = ML[(sw * 64 + lane) * 2 + 1];
    const float mM = fmaxf(m_run, m1);
    const float f0 = exp2f(m_run - mM), f1 = exp2f(m1 - mM);
    const float rl = 1.f / (l_run * f0 + l1 * f1);
    const float g0 = f0 * rl, g1 = f1 * rl;
#pragma unroll
    for (int r = 0; r < 16; ++r) {
      acc0[r] = acc0[r] * g0 + src[r] * g1;
      acc1[r] = acc1[r] * g0 + src[16 + r] * g1;
    }
    // transpose to [q][d] in LDS: D row = (r&3)+8*(r>>2)+4*hi (+32*dh)
#pragma unroll
    for (int dh = 0; dh < 2; ++dh) {
      const f32x16& A = dh ? acc1 : acc0;
#pragma unroll
      for (int g = 0; g < 4; ++g)
#pragma unroll
        for (int p = 0; p < 2; ++p) {
          int r0 = 4 * g + 2 * p;
          int d0 = 2 * p + 8 * g + 4 * hi + 32 * dh;
          unsigned u = pk2(A[r0], A[r0 + 1]);
          *reinterpret_cast<unsigned*>(&ob[(sw * 32 + lq) * 72 + d0]) = u;
        }
    }
  }
  __syncthreads();
  {
    const int row = tid >> 2, seg = tid & 3;
    short* dst = ctx + ((size_t)b * S_ + qt * 64 + row) * D_ + h * 64 + seg * 16;
    const short* srcp = &ob[row * 72 + seg * 16];
    *reinterpret_cast<bf16x8*>(dst) = *reinterpret_cast<const bf16x8*>(srcp);
    *reinterpret_cast<bf16x8*>(dst + 8) = *reinterpret_cast<const bf16x8*>(srcp + 8);
  }
}

extern "C" void kernel_launch(void* const* d_in, const int* in_sizes, int n_in,
                              void* d_out, int out_size, void* d_ws, size_t ws_size,
                              hipStream_t stream) {
  const float* X    = (const float*)d_in[0];
  const float* mask = (const float*)d_in[1];
  const float* Wqkv = (const float*)d_in[2];
  const float* bqkv = (const float*)d_in[3];
  const float* Wout = (const float*)d_in[4];
  const float* bout = (const float*)d_in[5];
  float* Out = (float*)d_out;

  short* ws    = (short*)d_ws;
  short* Xb    = ws;                                   // 4096*1024 bf16
  short* WqkvT = Xb + (size_t)4096 * 1024;             // [3072][1024]
  short* WoutT = WqkvT + (size_t)3072 * 1024;          // [1024][1024]
  short* Qh    = WoutT + (size_t)1024 * 1024;          // [bh][s][64]
  short* Kh    = Qh + (size_t)B_ * H_ * S_ * DEPTH_;   // [bh][s][64]
  short* VTt   = Kh + (size_t)B_ * H_ * S_ * DEPTH_;   // [bh][64][s]
  short* ctx   = VTt + (size_t)B_ * H_ * S_ * DEPTH_;  // [b][s][1024]

  cast_kernel<<<4096, 256, 0, stream>>>(X, Xb, (4096 * 1024) / 4);
  transpose_cast_kernel<<<dim3(96, 32), dim3(32, 8), 0, stream>>>(Wqkv, WqkvT, 1024, 3072);
  transpose_cast_kernel<<<dim3(32, 32), dim3(32, 8), 0, stream>>>(Wout, WoutT, 1024, 1024);
  gemm_bt_kernel<0><<<dim3(24, 32), 256, 0, stream>>>(Xb, WqkvT, bqkv, Qh, Kh, VTt, nullptr,
                                                      4096, 3072, 1024);
  attn_kernel<<<1024, 256, 0, stream>>>(Qh, Kh, VTt, mask, ctx);
  gemm_bt_kernel<1><<<dim3(8, 32), 256, 0, stream>>>(ctx, WoutT, bout, nullptr, nullptr, nullptr,
                                                     Out, 4096, 1024, 1024);
}

// Round 7
// 123.869 us; speedup vs baseline: 1.8461x; 1.2590x over previous
//
#include <hip/hip_runtime.h>
#include <hip/hip_bf16.h>

#define B_ 2
#define S_ 2048
#define D_ 1024
#define H_ 16
#define DEPTH_ 64

typedef __attribute__((ext_vector_type(4))) float f32x4;
typedef __attribute__((ext_vector_type(16))) float f32x16;
typedef __attribute__((ext_vector_type(8))) short bf16x8;
typedef const __attribute__((address_space(1))) unsigned int gu32;
typedef __attribute__((address_space(3))) unsigned int lu32;

__device__ __forceinline__ void gload_lds16(const void* g, void* l) {
  __builtin_amdgcn_global_load_lds((gu32*)g, (lu32*)l, 16, 0, 0);
}

__device__ __forceinline__ short f2bf(float f) {
  union { float f; unsigned u; } v; v.f = f;
  return (short)((v.u + 0x7FFFu + ((v.u >> 16) & 1u)) >> 16);
}
__device__ __forceinline__ unsigned pk2(float lo, float hi) {
  return ((unsigned)(unsigned short)f2bf(hi) << 16) | (unsigned short)f2bf(lo);
}

// ---------- cast fp32 -> bf16 (4 elems/thread) ----------
__global__ __launch_bounds__(256) void cast_kernel(const float* __restrict__ in,
                                                   short* __restrict__ out, int n4) {
  int i = blockIdx.x * 256 + threadIdx.x;
  if (i < n4) {
    const float4 v = reinterpret_cast<const float4*>(in)[i];
    short4 o;
    o.x = f2bf(v.x); o.y = f2bf(v.y); o.z = f2bf(v.z); o.w = f2bf(v.w);
    reinterpret_cast<short4*>(out)[i] = o;
  }
}

// ---------- transpose + cast: W[K][N] f32 -> WT[N][K] bf16 ----------
__global__ __launch_bounds__(256) void transpose_cast_kernel(const float* __restrict__ W,
                                                             short* __restrict__ WT,
                                                             int K, int N) {
  __shared__ short tile[32][33];
  int n0 = blockIdx.x * 32, k0 = blockIdx.y * 32;
  int tx = threadIdx.x, ty = threadIdx.y;
#pragma unroll
  for (int j = 0; j < 4; ++j)
    tile[ty + 8 * j][tx] = f2bf(W[(size_t)(k0 + ty + 8 * j) * N + n0 + tx]);
  __syncthreads();
#pragma unroll
  for (int j = 0; j < 4; ++j)
    WT[(size_t)(n0 + ty + 8 * j) * K + k0 + tx] = tile[tx][ty + 8 * j];
}

// ---------- GEMM, 2-phase double-buffered (T3 minimal recipe) ----------
// BK=32, 512 threads = 8 waves (4x2 grid of (BM/4)x64 tiles), LDS dbuf 32KB.
// EPI 0 (BM=128): scatter Q/K head-split; V via LDS transpose -> coalesced.
// EPI 1 (BM=64): fp32 out.
template <int EPI, int BM>
__global__ __launch_bounds__(512) void gemm_bt_kernel(
    const short* __restrict__ A, const short* __restrict__ BT,
    const float* __restrict__ bias,
    short* __restrict__ Qh, short* __restrict__ Kh, short* __restrict__ VTt,
    float* __restrict__ Out, int M, int N, int K) {
  constexpr int MI = BM / 64;        // m-frags per wave
  constexpr int ASZ = BM * 32;       // shorts per A buffer
  constexpr int BSZ = 128 * 32;
  __shared__ short smem[2 * ASZ + 2 * BSZ];
  const int bm = blockIdx.y * BM, bn = blockIdx.x * 128;
  const int tid = threadIdx.x;
  const int w = tid >> 6, lane = tid & 63;
  const int wr = w >> 1, wc = w & 1;
  const int lr = lane & 15, lg = lane >> 4;
  const int s_r = lane >> 2, s_c = (lane & 3) * 8;  // staging row/col within group
  f32x4 acc[MI][4] = {};
  const int nk = K >> 5;

  auto stage = [&](int buf, int kt) {
    short* Asb = smem + (buf ? ASZ : 0);
    short* Bsb = smem + 2 * ASZ + (buf ? BSZ : 0);
    if (BM == 128 || w < 4)
      gload_lds16(&A[(size_t)(bm + 16 * w + s_r) * K + kt * 32 + s_c], &Asb[16 * w * 32]);
    gload_lds16(&BT[(size_t)(bn + 16 * w + s_r) * K + kt * 32 + s_c], &Bsb[16 * w * 32]);
  };

  stage(0, 0);
  __syncthreads();
  int cur = 0;
  for (int kt = 0; kt < nk; ++kt) {
    if (kt + 1 < nk) stage(cur ^ 1, kt + 1);  // prefetch in flight during compute
    const short* Asb = smem + (cur ? ASZ : 0);
    const short* Bsb = smem + 2 * ASZ + (cur ? BSZ : 0);
    bf16x8 af[MI], bfr[4];
#pragma unroll
    for (int mi = 0; mi < MI; ++mi)
      af[mi] = *reinterpret_cast<const bf16x8*>(&Asb[((BM / 4) * wr + 16 * mi + lr) * 32 + 8 * lg]);
#pragma unroll
    for (int ni = 0; ni < 4; ++ni)
      bfr[ni] = *reinterpret_cast<const bf16x8*>(&Bsb[(64 * wc + 16 * ni + lr) * 32 + 8 * lg]);
#pragma unroll
    for (int mi = 0; mi < MI; ++mi)
#pragma unroll
      for (int ni = 0; ni < 4; ++ni)
        acc[mi][ni] = __builtin_amdgcn_mfma_f32_16x16x32_bf16(af[mi], bfr[ni], acc[mi][ni], 0, 0, 0);
    __syncthreads();  // vmcnt(0)+lgkmcnt(0)+barrier: next buffer ready, this one reusable
    cur ^= 1;
  }

  // epilogue: D layout col = lane&15, row = 4*(lane>>4)+r  [m89 verified]
  if constexpr (EPI == 0) {
    if (bn >= 2 * D_) {
      // whole block is V: transpose in LDS (XOR-swizzled), coalesced 16B stores
      __syncthreads();
      short* vt = smem;  // 128 x 128 shorts = 32KB
#pragma unroll
      for (int mi = 0; mi < MI; ++mi)
#pragma unroll
        for (int ni = 0; ni < 4; ++ni)
#pragma unroll
          for (int r = 0; r < 4; r += 2) {
            int row_local = (BM / 4) * wr + 16 * mi + 4 * lg + r;
            int col_local = 64 * wc + 16 * ni + lr;
            float bv = bias[bn + col_local];
            unsigned u = pk2(acc[mi][ni][r] + bv, acc[mi][ni][r + 1] + bv);
            int rsw = row_local ^ ((col_local & 7) << 3);
            *reinterpret_cast<unsigned*>(&vt[col_local * 128 + rsw]) = u;
          }
      __syncthreads();
      const int b = bm >> 11, sbase = bm & (S_ - 1);
#pragma unroll
      for (int p = 0; p < 4; ++p) {
        int slot = 512 * p + tid;
        int vrow = slot >> 4, seg = slot & 15;
        int dd_col = bn - 2 * D_ + vrow;
        int hh = dd_col >> 6, dd = dd_col & 63;
        int csw = (seg * 8) ^ ((vrow & 7) << 3);
        short* dst = &VTt[((size_t)(b * H_ + hh) * DEPTH_ + dd) * S_ + sbase + seg * 8];
        *reinterpret_cast<bf16x8*>(dst) = *reinterpret_cast<const bf16x8*>(&vt[vrow * 128 + csw]);
      }
    } else {
#pragma unroll
      for (int mi = 0; mi < MI; ++mi)
#pragma unroll
        for (int ni = 0; ni < 4; ++ni)
#pragma unroll
          for (int r = 0; r < 4; ++r) {
            int row = bm + (BM / 4) * wr + 16 * mi + 4 * lg + r;
            int col = bn + 64 * wc + 16 * ni + lr;
            float v = acc[mi][ni][r] + bias[col];
            int b = row >> 11, s = row & (S_ - 1);
            int which = col >> 10, cm = col & (D_ - 1);
            int hh = cm >> 6, dd = cm & 63;
            short bv = f2bf(v);
            size_t bh = (size_t)(b * H_ + hh);
            if (which == 0) Qh[(bh * S_ + s) * DEPTH_ + dd] = bv;
            else            Kh[(bh * S_ + s) * DEPTH_ + dd] = bv;
          }
    }
  } else {
#pragma unroll
    for (int mi = 0; mi < MI; ++mi)
#pragma unroll
      for (int ni = 0; ni < 4; ++ni)
#pragma unroll
        for (int r = 0; r < 4; ++r) {
          int row = bm + (BM / 4) * wr + 16 * mi + 4 * lg + r;
          int col = bn + 64 * wc + 16 * ni + lr;
          Out[(size_t)row * N + col] = acc[mi][ni][r] + bias[col];
        }
  }
}

// ---------- flash attention, 32x32 swapped-operand + split-KV ----------
__global__ __launch_bounds__(256, 4) void attn_kernel(
    const short* __restrict__ Qh, const short* __restrict__ Kh,
    const short* __restrict__ VTt, const float* __restrict__ mask,
    short* __restrict__ ctx) {
  constexpr float SC = 0.125f * 1.44269504f;  // scale * log2(e)
  __shared__ short smem[16384];  // 32KB: [chunk][K 4096 | V 4096] shorts
  const int bid = blockIdx.x;
  const int qt = 31 - (bid >> 5);
  const int bh = bid & 31;
  const int b = bh >> 4, h = bh & 15;
  const short* Qp = Qh + (size_t)bh * S_ * DEPTH_;
  const short* Kp = Kh + (size_t)bh * S_ * DEPTH_;
  const short* Vp = VTt + (size_t)bh * DEPTH_ * S_;
  const int tid = threadIdx.x;
  const int w = tid >> 6, lane = tid & 63;
  const int sw = w & 1, ch = w >> 1;
  const int lq = lane & 31, hi = lane >> 5;
  const int q0w = qt * 64 + sw * 32;
  const int scs = 8 * ((lane & 7) ^ ((lane >> 3) & 7));
  const int srw = lane >> 3;
  short* Ksc = smem + ch * 8192;
  short* Vsc = Ksc + 4096;

  bf16x8 qf[4];
#pragma unroll
  for (int ksd = 0; ksd < 4; ++ksd)
    qf[ksd] = *reinterpret_cast<const bf16x8*>(&Qp[(size_t)(q0w + lq) * DEPTH_ + 16 * ksd + 8 * hi]);

  bf16x8 ones = {};
  if (hi == 0) ones[0] = (short)0x3F80;

  f32x16 acc0 = {}, acc1 = {};
  float m_run = -1e30f, l_run = 0.f;

  const int nt = qt + 1;
  const int nh = (nt + 1) >> 1;
  for (int i = 0; i < nh; ++i) {
    const int kt = ch ? (nh + i) : i;
    const bool valid = kt < nt;
    const int k0 = kt * 64;
    __syncthreads();
    if (valid) {
#pragma unroll
      for (int j = 0; j < 4; ++j) {
        const int brow = sw * 32 + j * 8;
        gload_lds16(&Kp[(size_t)(k0 + brow + srw) * DEPTH_ + scs], &Ksc[brow * 64]);
        gload_lds16(&Vp[(size_t)(brow + srw) * S_ + k0 + scs], &Vsc[brow * 64]);
      }
    }
    __syncthreads();
    if (!valid) continue;

    f32x16 sc[2] = {{}, {}};
#pragma unroll
    for (int h2 = 0; h2 < 2; ++h2) {
#pragma unroll
      for (int ksd = 0; ksd < 4; ++ksd) {
        const int row = h2 * 32 + lq;
        const int col = (16 * ksd + 8 * hi) ^ ((row & 7) * 8);
        bf16x8 kf = *reinterpret_cast<const bf16x8*>(&Ksc[row * 64 + col]);
        sc[h2] = __builtin_amdgcn_mfma_f32_32x32x16_bf16(kf, qf[ksd], sc[h2], 0, 0, 0);
      }
      float mv = mask[(size_t)b * S_ + k0 + h2 * 32 + lq];
      bf16x8 maf = {};
      if (hi == 0) maf[0] = f2bf(8.f * mv);
      sc[h2] = __builtin_amdgcn_mfma_f32_32x32x16_bf16(maf, ones, sc[h2], 0, 0, 0);
    }
    if (kt == nt - 1) {
      const int qg = q0w + lq;
#pragma unroll
      for (int h2 = 0; h2 < 2; ++h2)
#pragma unroll
        for (int r = 0; r < 16; ++r) {
          int kvg = k0 + (r & 3) + 8 * (r >> 2) + 4 * hi + 32 * h2;
          if (kvg > qg) sc[h2][r] = -1e30f;
        }
    }
    float mx = sc[0][0];
#pragma unroll
    for (int r = 1; r < 16; ++r) mx = fmaxf(mx, sc[0][r]);
#pragma unroll
    for (int r = 0; r < 16; ++r) mx = fmaxf(mx, sc[1][r]);
    mx = fmaxf(mx, __shfl_xor(mx, 32));
    const float m_tile = mx * SC;
    const float m_new = fmaxf(m_run, m_tile);
    const float corr = exp2f(m_run - m_new);
    m_run = m_new;
    float su = 0.f;
#pragma unroll
    for (int h2 = 0; h2 < 2; ++h2)
#pragma unroll
      for (int r = 0; r < 16; ++r) {
        float p = exp2f(fmaf(sc[h2][r], SC, -m_new));
        sc[h2][r] = p;
        su += p;
      }
    su += __shfl_xor(su, 32);
    l_run = l_run * corr + su;
#pragma unroll
    for (int r = 0; r < 16; ++r) { acc0[r] *= corr; acc1[r] *= corr; }

#pragma unroll
    for (int h2 = 0; h2 < 2; ++h2) {
#pragma unroll
      for (int ks = 0; ks < 2; ++ks) {
        const int rb = 8 * ks;
        unsigned a = pk2(sc[h2][rb + 0], sc[h2][rb + 1]);
        unsigned bq = pk2(sc[h2][rb + 2], sc[h2][rb + 3]);
        unsigned c = pk2(sc[h2][rb + 4], sc[h2][rb + 5]);
        unsigned d = pk2(sc[h2][rb + 6], sc[h2][rb + 7]);
        unsigned sa = __shfl_xor((int)a, 32), sb = __shfl_xor((int)bq, 32);
        unsigned sx = __shfl_xor((int)c, 32), sy = __shfl_xor((int)d, 32);
        union { unsigned u[4]; bf16x8 v; } pf;
        pf.u[0] = hi ? sx : a;
        pf.u[1] = hi ? sy : bq;
        pf.u[2] = hi ? c : sa;
        pf.u[3] = hi ? d : sb;
#pragma unroll
        for (int dh = 0; dh < 2; ++dh) {
          const int row = dh * 32 + lq;
          const int col = (32 * h2 + 16 * ks + 8 * hi) ^ ((row & 7) * 8);
          bf16x8 vf = *reinterpret_cast<const bf16x8*>(&Vsc[row * 64 + col]);
          if (dh == 0) acc0 = __builtin_amdgcn_mfma_f32_32x32x16_bf16(vf, pf.v, acc0, 0, 0, 0);
          else         acc1 = __builtin_amdgcn_mfma_f32_32x32x16_bf16(vf, pf.v, acc1, 0, 0, 0);
        }
      }
    }
  }

  __syncthreads();
  float* F  = (float*)smem;
  float* ML = (float*)(smem + 8192);
  short* ob = smem + 8704;
  if (ch == 1) {
    float* dst = F + ((size_t)sw * 64 + lane) * 32;
#pragma unroll
    for (int r = 0; r < 16; ++r) { dst[r] = acc0[r]; dst[16 + r] = acc1[r]; }
    ML[(sw * 64 + lane) * 2 + 0] = m_run;
    ML[(sw * 64 + lane) * 2 + 1] = l_run;
  }
  __syncthreads();
  if (ch == 0) {
    const float* src = F + ((size_t)sw * 64 + lane) * 32;
    const float m1 = ML[(sw * 64 + lane) * 2 + 0];
    const float l1 = ML[(sw * 64 + lane) * 2 + 1];
    const float mM = fmaxf(m_run, m1);
    const float f0 = exp2f(m_run - mM), f1 = exp2f(m1 - mM);
    const float rl = 1.f / (l_run * f0 + l1 * f1);
    const float g0 = f0 * rl, g1 = f1 * rl;
#pragma unroll
    for (int r = 0; r < 16; ++r) {
      acc0[r] = acc0[r] * g0 + src[r] * g1;
      acc1[r] = acc1[r] * g0 + src[16 + r] * g1;
    }
#pragma unroll
    for (int dh = 0; dh < 2; ++dh) {
      const f32x16& Aa = dh ? acc1 : acc0;
#pragma unroll
      for (int g = 0; g < 4; ++g)
#pragma unroll
        for (int p = 0; p < 2; ++p) {
          int r0 = 4 * g + 2 * p;
          int d0 = 2 * p + 8 * g + 4 * hi + 32 * dh;
          unsigned u = pk2(Aa[r0], Aa[r0 + 1]);
          *reinterpret_cast<unsigned*>(&ob[(sw * 32 + lq) * 72 + d0]) = u;
        }
    }
  }
  __syncthreads();
  {
    const int row = tid >> 2, seg = tid & 3;
    short* dst = ctx + ((size_t)b * S_ + qt * 64 + row) * D_ + h * 64 + seg * 16;
    const short* srcp = &ob[row * 72 + seg * 16];
    *reinterpret_cast<bf16x8*>(dst) = *reinterpret_cast<const bf16x8*>(srcp);
    *reinterpret_cast<bf16x8*>(dst + 8) = *reinterpret_cast<const bf16x8*>(srcp + 8);
  }
}

extern "C" void kernel_launch(void* const* d_in, const int* in_sizes, int n_in,
                              void* d_out, int out_size, void* d_ws, size_t ws_size,
                              hipStream_t stream) {
  const float* X    = (const float*)d_in[0];
  const float* mask = (const float*)d_in[1];
  const float* Wqkv = (const float*)d_in[2];
  const float* bqkv = (const float*)d_in[3];
  const float* Wout = (const float*)d_in[4];
  const float* bout = (const float*)d_in[5];
  float* Out = (float*)d_out;

  short* ws    = (short*)d_ws;
  short* Xb    = ws;                                   // 4096*1024 bf16
  short* WqkvT = Xb + (size_t)4096 * 1024;             // [3072][1024]
  short* WoutT = WqkvT + (size_t)3072 * 1024;          // [1024][1024]
  short* Qh    = WoutT + (size_t)1024 * 1024;          // [bh][s][64]
  short* Kh    = Qh + (size_t)B_ * H_ * S_ * DEPTH_;   // [bh][s][64]
  short* VTt   = Kh + (size_t)B_ * H_ * S_ * DEPTH_;   // [bh][64][s]
  short* ctx   = VTt + (size_t)B_ * H_ * S_ * DEPTH_;  // [b][s][1024]

  cast_kernel<<<4096, 256, 0, stream>>>(X, Xb, (4096 * 1024) / 4);
  transpose_cast_kernel<<<dim3(96, 32), dim3(32, 8), 0, stream>>>(Wqkv, WqkvT, 1024, 3072);
  transpose_cast_kernel<<<dim3(32, 32), dim3(32, 8), 0, stream>>>(Wout, WoutT, 1024, 1024);
  gemm_bt_kernel<0, 128><<<dim3(24, 32), 512, 0, stream>>>(Xb, WqkvT, bqkv, Qh, Kh, VTt, nullptr,
                                                           4096, 3072, 1024);
  attn_kernel<<<1024, 256, 0, stream>>>(Qh, Kh, VTt, mask, ctx);
  gemm_bt_kernel<1, 64><<<dim3(8, 64), 512, 0, stream>>>(ctx, WoutT, bout, nullptr, nullptr, nullptr,
                                                         Out, 4096, 1024, 1024);
}

// Round 8
// 116.842 us; speedup vs baseline: 1.9571x; 1.0601x over previous
//
#include <hip/hip_runtime.h>
#include <hip/hip_bf16.h>

#define B_ 2
#define S_ 2048
#define D_ 1024
#define H_ 16
#define DEPTH_ 64

typedef __attribute__((ext_vector_type(4))) float f32x4;
typedef __attribute__((ext_vector_type(16))) float f32x16;
typedef __attribute__((ext_vector_type(8))) short bf16x8;
typedef const __attribute__((address_space(1))) unsigned int gu32;
typedef __attribute__((address_space(3))) unsigned int lu32;

__device__ __forceinline__ void gload_lds16(const void* g, void* l) {
  __builtin_amdgcn_global_load_lds((gu32*)g, (lu32*)l, 16, 0, 0);
}

__device__ __forceinline__ short f2bf(float f) {
  union { float f; unsigned u; } v; v.f = f;
  return (short)((v.u + 0x7FFFu + ((v.u >> 16) & 1u)) >> 16);
}
// hardware packed f32x2 -> bf16x2 (RNE), one VALU instr
__device__ __forceinline__ unsigned pk2(float lo, float hi) {
  unsigned r;
  asm("v_cvt_pk_bf16_f32 %0, %1, %2" : "=v"(r) : "v"(lo), "v"(hi));
  return r;
}

// ---------- cast fp32 -> bf16 (4 elems/thread) ----------
__global__ __launch_bounds__(256) void cast_kernel(const float* __restrict__ in,
                                                   short* __restrict__ out, int n4) {
  int i = blockIdx.x * 256 + threadIdx.x;
  if (i < n4) {
    const float4 v = reinterpret_cast<const float4*>(in)[i];
    short2 a, b;
    *reinterpret_cast<unsigned*>(&a) = pk2(v.x, v.y);
    *reinterpret_cast<unsigned*>(&b) = pk2(v.z, v.w);
    reinterpret_cast<short4*>(out)[i] = make_short4(a.x, a.y, b.x, b.y);
  }
}

// ---------- transpose + cast: W[K][N] f32 -> WT[N][K] bf16 ----------
__global__ __launch_bounds__(256) void transpose_cast_kernel(const float* __restrict__ W,
                                                             short* __restrict__ WT,
                                                             int K, int N) {
  __shared__ short tile[32][33];
  int n0 = blockIdx.x * 32, k0 = blockIdx.y * 32;
  int tx = threadIdx.x, ty = threadIdx.y;
#pragma unroll
  for (int j = 0; j < 4; ++j)
    tile[ty + 8 * j][tx] = f2bf(W[(size_t)(k0 + ty + 8 * j) * N + n0 + tx]);
  __syncthreads();
#pragma unroll
  for (int j = 0; j < 4; ++j)
    WT[(size_t)(n0 + ty + 8 * j) * K + k0 + tx] = tile[tx][ty + 8 * j];
}

// ---------- GEMM, 2-phase double-buffered (T3 minimal recipe) ----------
// BK=32, 512 threads = 8 waves (4x2 grid of (BM/4)x64 tiles), LDS dbuf 32KB.
template <int EPI, int BM>
__global__ __launch_bounds__(512) void gemm_bt_kernel(
    const short* __restrict__ A, const short* __restrict__ BT,
    const float* __restrict__ bias,
    short* __restrict__ Qh, short* __restrict__ Kh, short* __restrict__ VTt,
    float* __restrict__ Out, int M, int N, int K) {
  constexpr int MI = BM / 64;        // m-frags per wave
  constexpr int ASZ = BM * 32;       // shorts per A buffer
  constexpr int BSZ = 128 * 32;
  __shared__ short smem[2 * ASZ + 2 * BSZ];
  const int bm = blockIdx.y * BM, bn = blockIdx.x * 128;
  const int tid = threadIdx.x;
  const int w = tid >> 6, lane = tid & 63;
  const int wr = w >> 1, wc = w & 1;
  const int lr = lane & 15, lg = lane >> 4;
  const int s_r = lane >> 2, s_c = (lane & 3) * 8;
  f32x4 acc[MI][4] = {};
  const int nk = K >> 5;

  auto stage = [&](int buf, int kt) {
    short* Asb = smem + (buf ? ASZ : 0);
    short* Bsb = smem + 2 * ASZ + (buf ? BSZ : 0);
    if (BM == 128 || w < 4)
      gload_lds16(&A[(size_t)(bm + 16 * w + s_r) * K + kt * 32 + s_c], &Asb[16 * w * 32]);
    gload_lds16(&BT[(size_t)(bn + 16 * w + s_r) * K + kt * 32 + s_c], &Bsb[16 * w * 32]);
  };

  stage(0, 0);
  __syncthreads();
  int cur = 0;
  for (int kt = 0; kt < nk; ++kt) {
    if (kt + 1 < nk) stage(cur ^ 1, kt + 1);  // prefetch in flight during compute
    const short* Asb = smem + (cur ? ASZ : 0);
    const short* Bsb = smem + 2 * ASZ + (cur ? BSZ : 0);
    bf16x8 af[MI], bfr[4];
#pragma unroll
    for (int mi = 0; mi < MI; ++mi)
      af[mi] = *reinterpret_cast<const bf16x8*>(&Asb[((BM / 4) * wr + 16 * mi + lr) * 32 + 8 * lg]);
#pragma unroll
    for (int ni = 0; ni < 4; ++ni)
      bfr[ni] = *reinterpret_cast<const bf16x8*>(&Bsb[(64 * wc + 16 * ni + lr) * 32 + 8 * lg]);
#pragma unroll
    for (int mi = 0; mi < MI; ++mi)
#pragma unroll
      for (int ni = 0; ni < 4; ++ni)
        acc[mi][ni] = __builtin_amdgcn_mfma_f32_16x16x32_bf16(af[mi], bfr[ni], acc[mi][ni], 0, 0, 0);
    __syncthreads();
    cur ^= 1;
  }

  // epilogue: D layout col = lane&15, row = 4*(lane>>4)+r  [m89 verified]
  if constexpr (EPI == 0) {
    if (bn >= 2 * D_) {
      // whole block is V: transpose in LDS (XOR-swizzled), coalesced 16B stores
      __syncthreads();
      short* vt = smem;  // 128 x 128 shorts = 32KB
#pragma unroll
      for (int mi = 0; mi < MI; ++mi)
#pragma unroll
        for (int ni = 0; ni < 4; ++ni)
#pragma unroll
          for (int r = 0; r < 4; r += 2) {
            int row_local = (BM / 4) * wr + 16 * mi + 4 * lg + r;
            int col_local = 64 * wc + 16 * ni + lr;
            float bv = bias[bn + col_local];
            unsigned u = pk2(acc[mi][ni][r] + bv, acc[mi][ni][r + 1] + bv);
            int rsw = row_local ^ ((col_local & 7) << 3);
            *reinterpret_cast<unsigned*>(&vt[col_local * 128 + rsw]) = u;
          }
      __syncthreads();
      const int b = bm >> 11, sbase = bm & (S_ - 1);
#pragma unroll
      for (int p = 0; p < 4; ++p) {
        int slot = 512 * p + tid;
        int vrow = slot >> 4, seg = slot & 15;
        int dd_col = bn - 2 * D_ + vrow;
        int hh = dd_col >> 6, dd = dd_col & 63;
        int csw = (seg * 8) ^ ((vrow & 7) << 3);
        short* dst = &VTt[((size_t)(b * H_ + hh) * DEPTH_ + dd) * S_ + sbase + seg * 8];
        *reinterpret_cast<bf16x8*>(dst) = *reinterpret_cast<const bf16x8*>(&vt[vrow * 128 + csw]);
      }
    } else {
#pragma unroll
      for (int mi = 0; mi < MI; ++mi)
#pragma unroll
        for (int ni = 0; ni < 4; ++ni)
#pragma unroll
          for (int r = 0; r < 4; ++r) {
            int row = bm + (BM / 4) * wr + 16 * mi + 4 * lg + r;
            int col = bn + 64 * wc + 16 * ni + lr;
            float v = acc[mi][ni][r] + bias[col];
            int b = row >> 11, s = row & (S_ - 1);
            int which = col >> 10, cm = col & (D_ - 1);
            int hh = cm >> 6, dd = cm & 63;
            short bv = f2bf(v);
            size_t bh = (size_t)(b * H_ + hh);
            if (which == 0) Qh[(bh * S_ + s) * DEPTH_ + dd] = bv;
            else            Kh[(bh * S_ + s) * DEPTH_ + dd] = bv;
          }
    }
  } else {
#pragma unroll
    for (int mi = 0; mi < MI; ++mi)
#pragma unroll
      for (int ni = 0; ni < 4; ++ni)
#pragma unroll
        for (int r = 0; r < 4; ++r) {
          int row = bm + (BM / 4) * wr + 16 * mi + 4 * lg + r;
          int col = bn + 64 * wc + 16 * ni + lr;
          Out[(size_t)row * N + col] = acc[mi][ni][r] + bias[col];
        }
  }
}

// ---------- flash attention, 32x32 swapped-operand + split-KV ----------
// 1024 blocks = 32 (qt slots, CU-balanced map) x 32 bh; 4 waves = 2 q-strips x 2 kv-chunks.
__global__ __launch_bounds__(256, 4) void attn_kernel(
    const short* __restrict__ Qh, const short* __restrict__ Kh,
    const short* __restrict__ VTt, const float* __restrict__ mask,
    short* __restrict__ ctx) {
  constexpr float SC = 0.125f * 1.44269504f;  // scale * log2(e)
  __shared__ short smem[16384];  // 32KB: [chunk][K 4096 | V 4096] shorts
  const int bid = blockIdx.x;
  // CU-balanced qt map: stride-8 groups {31-g, 16+g, 15-g, g} sum equally
  const int j = bid >> 5, g = j & 7, rr = j >> 3;
  const int qt = (rr == 0) ? 31 - g : (rr == 1) ? 16 + g : (rr == 2) ? 15 - g : g;
  const int bh = bid & 31;
  const int b = bh >> 4, h = bh & 15;
  const short* Qp = Qh + (size_t)bh * S_ * DEPTH_;
  const short* Kp = Kh + (size_t)bh * S_ * DEPTH_;
  const short* Vp = VTt + (size_t)bh * DEPTH_ * S_;
  const int tid = threadIdx.x;
  const int w = tid >> 6, lane = tid & 63;
  const int sw = w & 1, ch = w >> 1;
  const int lq = lane & 31, hi = lane >> 5;
  const int q0w = qt * 64 + sw * 32;
  const int scs = 8 * ((lane & 7) ^ ((lane >> 3) & 7));
  const int srw = lane >> 3;
  short* Ksc = smem + ch * 8192;
  short* Vsc = Ksc + 4096;

  bf16x8 qf[4];
#pragma unroll
  for (int ksd = 0; ksd < 4; ++ksd)
    qf[ksd] = *reinterpret_cast<const bf16x8*>(&Qp[(size_t)(q0w + lq) * DEPTH_ + 16 * ksd + 8 * hi]);

  bf16x8 ones = {};
  if (hi == 0) ones[0] = (short)0x3F80;

  f32x16 acc0 = {}, acc1 = {};
  float m_run = -1e30f, l_run = 0.f;

  const int nt = qt + 1;
  const int nh = (nt + 1) >> 1;
  for (int i = 0; i < nh; ++i) {
    const int kt = ch ? (nh + i) : i;
    const bool valid = kt < nt;
    const int k0 = kt * 64;
    __syncthreads();
    if (valid) {
#pragma unroll
      for (int jj = 0; jj < 4; ++jj) {
        const int brow = sw * 32 + jj * 8;
        gload_lds16(&Kp[(size_t)(k0 + brow + srw) * DEPTH_ + scs], &Ksc[brow * 64]);
        gload_lds16(&Vp[(size_t)(brow + srw) * S_ + k0 + scs], &Vsc[brow * 64]);
      }
    }
    __syncthreads();
    if (!valid) continue;

    f32x16 sc[2] = {{}, {}};
#pragma unroll
    for (int h2 = 0; h2 < 2; ++h2) {
#pragma unroll
      for (int ksd = 0; ksd < 4; ++ksd) {
        const int row = h2 * 32 + lq;
        const int col = (16 * ksd + 8 * hi) ^ ((row & 7) * 8);
        bf16x8 kf = *reinterpret_cast<const bf16x8*>(&Ksc[row * 64 + col]);
        sc[h2] = __builtin_amdgcn_mfma_f32_32x32x16_bf16(kf, qf[ksd], sc[h2], 0, 0, 0);
      }
      float mv = mask[(size_t)b * S_ + k0 + h2 * 32 + lq];
      bf16x8 maf = {};
      if (hi == 0) maf[0] = f2bf(8.f * mv);
      sc[h2] = __builtin_amdgcn_mfma_f32_32x32x16_bf16(maf, ones, sc[h2], 0, 0, 0);
    }
    if (kt == nt - 1) {
      const int qg = q0w + lq;
#pragma unroll
      for (int h2 = 0; h2 < 2; ++h2)
#pragma unroll
        for (int r = 0; r < 16; ++r) {
          int kvg = k0 + (r & 3) + 8 * (r >> 2) + 4 * hi + 32 * h2;
          if (kvg > qg) sc[h2][r] = -1e30f;
        }
    }
    // wave-wide max of this lane's 32 kv values + partner combine
    float mx = fmaxf(sc[0][0], sc[0][1]);
#pragma unroll
    for (int r = 2; r < 16; ++r) mx = fmaxf(mx, sc[0][r]);
#pragma unroll
    for (int r = 0; r < 16; ++r) mx = fmaxf(mx, sc[1][r]);
    mx = fmaxf(mx, __shfl_xor(mx, 32));
    const float m_tile = mx * SC;
    // defer-max (T13): only rescale when some q-row grew past THR=8
    if (__any(m_tile > m_run + 8.f)) {
      const float m_new = fmaxf(m_run, m_tile);
      const float corr = exp2f(m_run - m_new);
      m_run = m_new;
      l_run *= corr;
#pragma unroll
      for (int r = 0; r < 16; ++r) { acc0[r] *= corr; acc1[r] *= corr; }
    }
    float su = 0.f;
#pragma unroll
    for (int h2 = 0; h2 < 2; ++h2)
#pragma unroll
      for (int r = 0; r < 16; ++r) {
        float p = exp2f(fmaf(sc[h2][r], SC, -m_run));
        sc[h2][r] = p;
        su += p;
      }
    su += __shfl_xor(su, 32);
    l_run += su;

    // PV: pack P rows into B-frags in-register (hw cvt_pk)
#pragma unroll
    for (int h2 = 0; h2 < 2; ++h2) {
#pragma unroll
      for (int ks = 0; ks < 2; ++ks) {
        const int rb = 8 * ks;
        unsigned a = pk2(sc[h2][rb + 0], sc[h2][rb + 1]);
        unsigned bq = pk2(sc[h2][rb + 2], sc[h2][rb + 3]);
        unsigned c = pk2(sc[h2][rb + 4], sc[h2][rb + 5]);
        unsigned d = pk2(sc[h2][rb + 6], sc[h2][rb + 7]);
        unsigned sa = __shfl_xor((int)a, 32), sb = __shfl_xor((int)bq, 32);
        unsigned sx = __shfl_xor((int)c, 32), sy = __shfl_xor((int)d, 32);
        union { unsigned u[4]; bf16x8 v; } pf;
        pf.u[0] = hi ? sx : a;
        pf.u[1] = hi ? sy : bq;
        pf.u[2] = hi ? c : sa;
        pf.u[3] = hi ? d : sb;
#pragma unroll
        for (int dh = 0; dh < 2; ++dh) {
          const int row = dh * 32 + lq;
          const int col = (32 * h2 + 16 * ks + 8 * hi) ^ ((row & 7) * 8);
          bf16x8 vf = *reinterpret_cast<const bf16x8*>(&Vsc[row * 64 + col]);
          if (dh == 0) acc0 = __builtin_amdgcn_mfma_f32_32x32x16_bf16(vf, pf.v, acc0, 0, 0, 0);
          else         acc1 = __builtin_amdgcn_mfma_f32_32x32x16_bf16(vf, pf.v, acc1, 0, 0, 0);
        }
      }
    }
  }

  __syncthreads();
  float* F  = (float*)smem;
  float* ML = (float*)(smem + 8192);
  short* ob = smem + 8704;
  if (ch == 1) {
    float* dst = F + ((size_t)sw * 64 + lane) * 32;
#pragma unroll
    for (int r = 0; r < 16; ++r) { dst[r] = acc0[r]; dst[16 + r] = acc1[r]; }
    ML[(sw * 64 + lane) * 2 + 0] = m_run;
    ML[(sw * 64 + lane) * 2 + 1] = l_run;
  }
  __syncthreads();
  if (ch == 0) {
    const float* src = F + ((size_t)sw * 64 + lane) * 32;
    const float m1 = ML[(sw * 64 + lane) * 2 + 0];
    const float l1 = ML[(sw * 64 + lane) * 2 + 1];
    const float mM = fmaxf(m_run, m1);
    const float f0 = exp2f(m_run - mM), f1 = exp2f(m1 - mM);
    const float rl = 1.f / (l_run * f0 + l1 * f1);
    const float g0 = f0 * rl, g1 = f1 * rl;
#pragma unroll
    for (int r = 0; r < 16; ++r) {
      acc0[r] = acc0[r] * g0 + src[r] * g1;
      acc1[r] = acc1[r] * g0 + src[16 + r] * g1;
    }
#pragma unroll
    for (int dh = 0; dh < 2; ++dh) {
      const f32x16& Aa = dh ? acc1 : acc0;
#pragma unroll
      for (int gg = 0; gg < 4; ++gg)
#pragma unroll
        for (int p = 0; p < 2; ++p) {
          int r0 = 4 * gg + 2 * p;
          int d0 = 2 * p + 8 * gg + 4 * hi + 32 * dh;
          unsigned u = pk2(Aa[r0], Aa[r0 + 1]);
          *reinterpret_cast<unsigned*>(&ob[(sw * 32 + lq) * 72 + d0]) = u;
        }
    }
  }
  __syncthreads();
  {
    const int row = tid >> 2, seg = tid & 3;
    short* dst = ctx + ((size_t)b * S_ + qt * 64 + row) * D_ + h * 64 + seg * 16;
    const short* srcp = &ob[row * 72 + seg * 16];
    *reinterpret_cast<bf16x8*>(dst) = *reinterpret_cast<const bf16x8*>(srcp);
    *reinterpret_cast<bf16x8*>(dst + 8) = *reinterpret_cast<const bf16x8*>(srcp + 8);
  }
}

extern "C" void kernel_launch(void* const* d_in, const int* in_sizes, int n_in,
                              void* d_out, int out_size, void* d_ws, size_t ws_size,
                              hipStream_t stream) {
  const float* X    = (const float*)d_in[0];
  const float* mask = (const float*)d_in[1];
  const float* Wqkv = (const float*)d_in[2];
  const float* bqkv = (const float*)d_in[3];
  const float* Wout = (const float*)d_in[4];
  const float* bout = (const float*)d_in[5];
  float* Out = (float*)d_out;

  short* ws    = (short*)d_ws;
  short* Xb    = ws;                                   // 4096*1024 bf16
  short* WqkvT = Xb + (size_t)4096 * 1024;             // [3072][1024]
  short* WoutT = WqkvT + (size_t)3072 * 1024;          // [1024][1024]
  short* Qh    = WoutT + (size_t)1024 * 1024;          // [bh][s][64]
  short* Kh    = Qh + (size_t)B_ * H_ * S_ * DEPTH_;   // [bh][s][64]
  short* VTt   = Kh + (size_t)B_ * H_ * S_ * DEPTH_;   // [bh][64][s]
  short* ctx   = VTt + (size_t)B_ * H_ * S_ * DEPTH_;  // [b][s][1024]

  cast_kernel<<<4096, 256, 0, stream>>>(X, Xb, (4096 * 1024) / 4);
  transpose_cast_kernel<<<dim3(96, 32), dim3(32, 8), 0, stream>>>(Wqkv, WqkvT, 1024, 3072);
  transpose_cast_kernel<<<dim3(32, 32), dim3(32, 8), 0, stream>>>(Wout, WoutT, 1024, 1024);
  gemm_bt_kernel<0, 128><<<dim3(24, 32), 512, 0, stream>>>(Xb, WqkvT, bqkv, Qh, Kh, VTt, nullptr,
                                                           4096, 3072, 1024);
  attn_kernel<<<1024, 256, 0, stream>>>(Qh, Kh, VTt, mask, ctx);
  gemm_bt_kernel<1, 64><<<dim3(8, 64), 512, 0, stream>>>(ctx, WoutT, bout, nullptr, nullptr, nullptr,
                                                         Out, 4096, 1024, 1024);
}